// Round 5
// baseline (2372.246 us; speedup 1.0000x reference)
//
#include <hip/hip_runtime.h>

typedef unsigned short u16;
typedef __attribute__((ext_vector_type(8))) __bf16 bf16x8;
typedef __attribute__((ext_vector_type(4))) float f32x4;

#define DT_STEP 0.01f

// ---- workspace layout (bytes) ----
// All matrix operands live in "MFMA-staged layout": element (row, kk) of a
// [rows x K] K-major matrix is stored in 1KB blocks of 16 rows x 32 kk:
//   off_u16 = ((row>>4)*KB + (kk>>5))*512 + (((kk>>3)&3)*16 + (row&15))*8 + (kk&7)
// so a wave's MFMA fragment load is exactly 16B per lane at base + lane*16B.
//
// Wall : 3968 rows x 512 K (KB=16)  : row k*496+i = sqrt(r_k)*L_k[i,:]
// Aop2 : 496 rows x 5632 K (KB=176) : KB 0..127 = SwC (setup) then Tflat (steps)
//                                     KB 128..143 = -0.5*G
//                                     KB 144..159 = -0.5*rho slot0
//                                     KB 160..175 = -0.5*rho slot1
// Bop2 : 496 rows x 5632 K (KB=176) : KB 0..127 = SwT (sqrt(r_k)*L_k blocks)
//                                     KB 128..143 = G
//                                     KB 144..159 = rho slot0
//                                     KB 160..175 = rho slot1
// pad  : keeps benign OOB reads of row-block 31 (rows 496..511, results
//        discarded by row<496 guards) inside the mapped workspace.
// bar  : grid-barrier monotonic epoch counter (int, zeroed by k0c each call).
static const size_t OFF_WALL = 0;
static const size_t OFF_AOP2 = 4063232;    // 248*16*512*2
static const size_t OFF_BOP2 = 9650176;    // + 31*176*512*2
static const size_t OFF_PAD  = 15237120;   // + 31*176*512*2
static const size_t OFF_BAR  = 16221184;   // near end of pad region
static const size_t WS_NEED  = 16221440;

static __device__ __forceinline__ u16 f2bf(float x){
  unsigned u = __float_as_uint(x);
  u = u + 0x7FFFu + ((u >> 16) & 1u);   // RNE
  return (u16)(u >> 16);
}

static __device__ __forceinline__ size_t stx(int row, int kk, int KB){
  return ((size_t)((row >> 4) * KB + (kk >> 5)) << 9)
       + (size_t)(((((kk >> 3) & 3) * 16) + (row & 15)) << 3) + (kk & 7);
}

// K0a: fill Wall (staged) and SwT region of Bop2 (staged). K-pads -> 0.
__global__ __launch_bounds__(256) void k0a(const float* __restrict__ L,
                                           const float* __restrict__ rates,
                                           u16* __restrict__ Wall,
                                           u16* __restrict__ Bop2){
  int id = blockIdx.x * 256 + threadIdx.x;
  if (id >= 8*496*512) return;
  int k   = id / (496*512);
  int rem = id - k*(496*512);
  int i   = rem >> 9;
  int j   = rem & 511;
  float rt = sqrtf(fabsf(rates[k]));
  float v = 0.0f;
  if (j < 496) v = rt * L[(size_t)k*246016 + i*496 + j];
  u16 h = f2bf(v);
  Wall[stx(k*496 + i, j, 16)] = h;
  Bop2[stx(i, (k << 9) + j, 176)] = h;
}

// K0b: SwC[i, k*512+j] = sqrt(r_k)*L_k[j,i] into Aop2 KB 0..127 (LDS transpose).
__global__ __launch_bounds__(256) void k0b(const float* __restrict__ L,
                                           const float* __restrict__ rates,
                                           u16* __restrict__ Aop2){
  __shared__ float tile[32][33];
  int k  = blockIdx.z;
  int i0 = blockIdx.x * 32;
  int j0 = blockIdx.y * 32;
  int tx = threadIdx.x, ty = threadIdx.y;  // 32 x 8
  float rt = sqrtf(fabsf(rates[k]));
  #pragma unroll
  for (int p = 0; p < 4; ++p){
    int j = j0 + ty + p*8;   // row of L_k
    int i = i0 + tx;         // col of L_k
    float v = 0.0f;
    if (j < 496 && i < 496) v = rt * L[(size_t)k*246016 + j*496 + i];
    tile[ty + p*8][tx] = v;
  }
  __syncthreads();
  #pragma unroll
  for (int p = 0; p < 4; ++p){
    int i = i0 + ty + p*8;   // SwC row
    int j = j0 + tx;         // col within k-block (pads get 0 via load guard)
    if (i < 496) Aop2[stx(i, (k << 9) + j, 176)] = f2bf(tile[tx][ty + p*8]);
  }
}

// K0c: rho into slot0 (staged), zero slot1 + G pads, d_out = rho0, bar = 0.
__global__ __launch_bounds__(256) void k0c(const float* __restrict__ rho0,
                                           u16* __restrict__ Aop2,
                                           u16* __restrict__ Bop2,
                                           float* __restrict__ dout,
                                           int* __restrict__ bar){
  int id = blockIdx.x * 256 + threadIdx.x;
  if (id >= 496*512) return;
  int i = id >> 9, j = id & 511;
  float f = (j < 496) ? rho0[(size_t)i*496 + j] : 0.0f;
  Bop2[stx(i, 4608 + j, 176)] = f2bf(f);
  Aop2[stx(i, 4608 + j, 176)] = f2bf(-0.5f*f);
  Bop2[stx(i, 5120 + j, 176)] = 0;
  Aop2[stx(i, 5120 + j, 176)] = 0;
  if (j >= 496){ Bop2[stx(i, 4096 + j, 176)] = 0; Aop2[stx(i, 4096 + j, 176)] = 0; }
  if (j < 496) dout[(size_t)i*496 + j] = f;
  if (id == 0) *bar = 0;
}

// Monotonic-epoch grid barrier: device-scope release fence + arrive, spin
// until all nblk arrivals of this epoch, acquire fence. Same fence/atomic
// pattern proven cross-XCD-correct by the R0/R2 split-K finalizers.
static __device__ __forceinline__ void gbar(int* bar, int target){
  __syncthreads();
  if (threadIdx.x == 0){
    __threadfence();
    __hip_atomic_fetch_add(bar, 1, __ATOMIC_RELAXED, __HIP_MEMORY_SCOPE_AGENT);
    while (__hip_atomic_load(bar, __ATOMIC_RELAXED, __HIP_MEMORY_SCOPE_AGENT) < target)
      __builtin_amdgcn_s_sleep(2);
    __threadfence();
  }
  __syncthreads();
}

// One NT-GEMM tile job on staged operands, rotated register pipeline.
// MODE 0: phase A, T_k = L~_k * rho. NKT=16. Epilogue -> staged Tflat
//         (pad cols written as 0 -> no NaN hazard).
// MODE 1: G = SwC * SwC^T (once). NKT=128. Epilogue -> -0.5G / G staged.
template<int MODE>
static __device__ __forceinline__ void gemm_job(
    int tm, int tn, int rhoKB,
    const u16* __restrict__ Ast, const u16* __restrict__ Bst,
    u16* Aop2, u16* Bop2)
{
  const int t    = threadIdx.x;
  const int lane = t & 63;
  const int w    = t >> 6;
  const int wm   = w & 1, wn = w >> 1;

  constexpr int DEPTH = 4;
  constexpr int NKT   = (MODE == 0) ? 16 : 128;
  const int KBa = (MODE == 0) ? 16 : 176;
  const int RA0 = tm*4 + wm*2;
  const int RB0 = tn*4 + wn*2;
  const size_t laneu = (size_t)lane * 8;
  const size_t strA = (size_t)KBa << 9;
  const size_t strB = (size_t)176 << 9;
  const u16* baseA = Ast + (((size_t)RA0 * KBa) << 9) + laneu;
  const u16* baseB = Bst + (((size_t)RB0 * 176) << 9) + laneu
                   + ((MODE == 0) ? ((size_t)rhoKB << 9) : (size_t)0);

  bf16x8 Ar[DEPTH][2], Br[DEPTH][2];
  f32x4 acc[2][2];
  #pragma unroll
  for (int a = 0; a < 2; ++a)
    #pragma unroll
    for (int b = 0; b < 2; ++b)
      acc[a][b] = (f32x4){0.f, 0.f, 0.f, 0.f};

  #pragma unroll
  for (int p = 0; p < DEPTH; ++p){
    const u16* pa = baseA + ((size_t)p << 9);
    const u16* pb = baseB + ((size_t)p << 9);
    Ar[p][0] = *(const bf16x8*)(pa);
    Ar[p][1] = *(const bf16x8*)(pa + strA);
    Br[p][0] = *(const bf16x8*)(pb);
    Br[p][1] = *(const bf16x8*)(pb + strB);
  }
  for (int it = 0; it < NKT - DEPTH; it += DEPTH){
    #pragma unroll
    for (int p = 0; p < DEPTH; ++p){
      acc[0][0] = __builtin_amdgcn_mfma_f32_16x16x32_bf16(Ar[p][0], Br[p][0], acc[0][0], 0, 0, 0);
      acc[0][1] = __builtin_amdgcn_mfma_f32_16x16x32_bf16(Ar[p][0], Br[p][1], acc[0][1], 0, 0, 0);
      acc[1][0] = __builtin_amdgcn_mfma_f32_16x16x32_bf16(Ar[p][1], Br[p][0], acc[1][0], 0, 0, 0);
      acc[1][1] = __builtin_amdgcn_mfma_f32_16x16x32_bf16(Ar[p][1], Br[p][1], acc[1][1], 0, 0, 0);
      int kt = it + p + DEPTH;
      const u16* pa = baseA + ((size_t)kt << 9);
      const u16* pb = baseB + ((size_t)kt << 9);
      Ar[p][0] = *(const bf16x8*)(pa);
      Ar[p][1] = *(const bf16x8*)(pa + strA);
      Br[p][0] = *(const bf16x8*)(pb);
      Br[p][1] = *(const bf16x8*)(pb + strB);
    }
  }
  #pragma unroll
  for (int p = 0; p < DEPTH; ++p){
    acc[0][0] = __builtin_amdgcn_mfma_f32_16x16x32_bf16(Ar[p][0], Br[p][0], acc[0][0], 0, 0, 0);
    acc[0][1] = __builtin_amdgcn_mfma_f32_16x16x32_bf16(Ar[p][0], Br[p][1], acc[0][1], 0, 0, 0);
    acc[1][0] = __builtin_amdgcn_mfma_f32_16x16x32_bf16(Ar[p][1], Br[p][0], acc[1][0], 0, 0, 0);
    acc[1][1] = __builtin_amdgcn_mfma_f32_16x16x32_bf16(Ar[p][1], Br[p][1], acc[1][1], 0, 0, 0);
  }

  const int quad = lane >> 4, c16 = lane & 15;
  #pragma unroll
  for (int mi = 0; mi < 2; ++mi)
  #pragma unroll
  for (int ni = 0; ni < 2; ++ni)
  #pragma unroll
  for (int r = 0; r < 4; ++r){
    int row = tm*64 + wm*32 + mi*16 + quad*4 + r;
    int col = tn*64 + wn*32 + ni*16 + c16;
    float v = acc[mi][ni][r];
    if (MODE == 0){
      int k  = row / 496;
      int i2 = row - k*496;
      u16 hv = (col < 496) ? f2bf(v) : (u16)0;   // zero pads: no NaN into Tflat
      Aop2[stx(i2, (k << 9) + col, 176)] = hv;
    } else {
      if (row < 496 && col < 496){
        Bop2[stx(row, 4096 + col, 176)] = f2bf(v);
        Aop2[stx(row, 4096 + col, 176)] = f2bf(-0.5f*v);
      }
    }
  }
}

// Phase-B job: rho += DT*( sum_k T_k L~_k^T - 0.5(G rho + rho G) ), symmetric.
// pairIdx in [0,136) = lower-tri pair of 32x32 C-tiles. Full K=5120 split
// across the block's 4 waves (DEPTH=5 register pipeline), LDS reduce,
// inline finalize (fp32 rho in dout + staged bf16 rho + mirror tile).
static __device__ __forceinline__ void jobB(
    int pairIdx, int rhoKB, int rhoKBN,
    u16* Aop2, u16* Bop2, float* dout)
{
  __shared__ float red[4][32][33];
  const int t = threadIdx.x, lane = t & 63, w = t >> 6;
  int b = pairIdx, tm = 0;
  while (b >= 16 - tm){ b -= 16 - tm; ++tm; }
  const int tn = tm + b;                     // tm <= tn

  const int kt0 = w * 40;                    // per-wave K slice (40 kt of 32)
  const size_t laneu = (size_t)lane * 8;
  const size_t str = (size_t)176 << 9;
  const u16* baseA = (const u16*)Aop2 + (((size_t)(tm*2) * 176) << 9) + laneu;
  const u16* baseB = (const u16*)Bop2 + (((size_t)(tn*2) * 176) << 9) + laneu;

  auto colmap = [&](int kt, int& ka, int& kb){
    if (kt < 128)      { ka = kt;               kb = kt; }             // T x SwT
    else if (kt < 144) { ka = kt;               kb = rhoKB + kt-128; } // -G/2 x rho
    else               { ka = rhoKB + kt - 144; kb = kt - 16; }        // -rho/2 x G
  };

  constexpr int DEPTH = 5;
  bf16x8 Ar[DEPTH][2], Br[DEPTH][2];
  f32x4 acc[2][2];
  #pragma unroll
  for (int a = 0; a < 2; ++a)
    #pragma unroll
    for (int c = 0; c < 2; ++c)
      acc[a][c] = (f32x4){0.f, 0.f, 0.f, 0.f};

  #pragma unroll
  for (int p = 0; p < DEPTH; ++p){
    int ka, kb; colmap(kt0 + p, ka, kb);
    const u16* pa = baseA + ((size_t)ka << 9);
    const u16* pb = baseB + ((size_t)kb << 9);
    Ar[p][0] = *(const bf16x8*)(pa);
    Ar[p][1] = *(const bf16x8*)(pa + str);
    Br[p][0] = *(const bf16x8*)(pb);
    Br[p][1] = *(const bf16x8*)(pb + str);
  }
  for (int it = 0; it < 40 - DEPTH; it += DEPTH){
    #pragma unroll
    for (int p = 0; p < DEPTH; ++p){
      acc[0][0] = __builtin_amdgcn_mfma_f32_16x16x32_bf16(Ar[p][0], Br[p][0], acc[0][0], 0, 0, 0);
      acc[0][1] = __builtin_amdgcn_mfma_f32_16x16x32_bf16(Ar[p][0], Br[p][1], acc[0][1], 0, 0, 0);
      acc[1][0] = __builtin_amdgcn_mfma_f32_16x16x32_bf16(Ar[p][1], Br[p][0], acc[1][0], 0, 0, 0);
      acc[1][1] = __builtin_amdgcn_mfma_f32_16x16x32_bf16(Ar[p][1], Br[p][1], acc[1][1], 0, 0, 0);
      int ka, kb; colmap(kt0 + it + p + DEPTH, ka, kb);
      const u16* pa = baseA + ((size_t)ka << 9);
      const u16* pb = baseB + ((size_t)kb << 9);
      Ar[p][0] = *(const bf16x8*)(pa);
      Ar[p][1] = *(const bf16x8*)(pa + str);
      Br[p][0] = *(const bf16x8*)(pb);
      Br[p][1] = *(const bf16x8*)(pb + str);
    }
  }
  #pragma unroll
  for (int p = 0; p < DEPTH; ++p){
    acc[0][0] = __builtin_amdgcn_mfma_f32_16x16x32_bf16(Ar[p][0], Br[p][0], acc[0][0], 0, 0, 0);
    acc[0][1] = __builtin_amdgcn_mfma_f32_16x16x32_bf16(Ar[p][0], Br[p][1], acc[0][1], 0, 0, 0);
    acc[1][0] = __builtin_amdgcn_mfma_f32_16x16x32_bf16(Ar[p][1], Br[p][0], acc[1][0], 0, 0, 0);
    acc[1][1] = __builtin_amdgcn_mfma_f32_16x16x32_bf16(Ar[p][1], Br[p][1], acc[1][1], 0, 0, 0);
  }

  const int quad = lane >> 4, c16 = lane & 15;
  #pragma unroll
  for (int mi = 0; mi < 2; ++mi)
  #pragma unroll
  for (int ni = 0; ni < 2; ++ni)
  #pragma unroll
  for (int r = 0; r < 4; ++r)
    red[w][mi*16 + quad*4 + r][ni*16 + c16] = acc[mi][ni][r];
  __syncthreads();

  #pragma unroll
  for (int c = t; c < 1024; c += 256){
    int lr = c >> 5, lc = c & 31;
    float sum = red[0][lr][lc] + red[1][lr][lc] + red[2][lr][lc] + red[3][lr][lc];
    int row = tm*32 + lr, col = tn*32 + lc;
    if (row < 496 && col < 496){
      int e = row*496 + col;
      float rnew = dout[e] + DT_STEP * sum;
      u16 hb = f2bf(rnew), ha = f2bf(-0.5f*rnew);
      dout[e] = rnew;
      Bop2[stx(row, (rhoKBN << 5) + col, 176)] = hb;
      Aop2[stx(row, (rhoKBN << 5) + col, 176)] = ha;
      if (tm != tn){
        dout[col*496 + row] = rnew;
        Bop2[stx(col, (rhoKBN << 5) + row, 176)] = hb;
        Aop2[stx(col, (rhoKBN << 5) + row, 176)] = ha;
      }
    }
  }
  __syncthreads();   // red reused next step
}

// Persistent cooperative kernel: G once + 32 x (phaseA, barrier, phaseB,
// barrier). 256 blocks (1/CU), monotonic-epoch grid barrier between phases.
__global__ __launch_bounds__(256, 1) void evolve(
    const u16* __restrict__ Wall, u16* Aop2, u16* Bop2,
    float* dout, int* bar)
{
  const int bid = blockIdx.x;
  int ep = 0;
  if (bid < 64) gemm_job<1>(bid >> 3, bid & 7, 0, Aop2, Aop2, Aop2, Bop2);
  gbar(bar, ++ep * 256);
  for (int s = 0; s < 32; ++s){
    int rhoKB  = 144 + 16*(s & 1);
    int rhoKBN = 144 + 16*((s+1) & 1);
    gemm_job<0>(bid % 62, bid / 62, rhoKB, Wall, Bop2, Aop2, Bop2);
    if (bid < 240){
      int j = bid + 256;
      gemm_job<0>(j % 62, j / 62, rhoKB, Wall, Bop2, Aop2, Bop2);
    }
    gbar(bar, ++ep * 256);
    if (bid < 136) jobB(bid, rhoKB, rhoKBN, Aop2, Bop2, dout);
    gbar(bar, ++ep * 256);
  }
}

// ---- fallback path (if cooperative launch is rejected) ----
template<int MODE>
__global__ __launch_bounds__(256, 2) void gemm_nt_k(
    const u16* __restrict__ Ast, const u16* __restrict__ Bst,
    int rhoKB, u16* Aop2, u16* Bop2){
  gemm_job<MODE>(blockIdx.x, blockIdx.y, rhoKB, Ast, Bst, Aop2, Bop2);
}
__global__ __launch_bounds__(256, 1) void phaseB_k(
    u16* Aop2, u16* Bop2, float* dout, int rhoKB, int rhoKBN){
  jobB(blockIdx.x, rhoKB, rhoKBN, Aop2, Bop2, dout);
}

extern "C" void kernel_launch(void* const* d_in, const int* in_sizes, int n_in,
                              void* d_out, int out_size, void* d_ws, size_t ws_size,
                              hipStream_t stream)
{
  (void)in_sizes; (void)n_in; (void)out_size;
  if (ws_size < WS_NEED) return;
  const float* rho0  = (const float*)d_in[0];
  // d_in[1] (H_real) provably does not affect the real forward output.
  const float* L     = (const float*)d_in[2];
  const float* rates = (const float*)d_in[3];
  float* dout = (float*)d_out;
  char* ws = (char*)d_ws;
  u16* Wall = (u16*)(ws + OFF_WALL);
  u16* Aop2 = (u16*)(ws + OFF_AOP2);
  u16* Bop2 = (u16*)(ws + OFF_BOP2);
  int* bar  = (int*)(ws + OFF_BAR);

  k0a<<<dim3((8*496*512 + 255)/256), dim3(256), 0, stream>>>(L, rates, Wall, Bop2);
  k0b<<<dim3(16,16,8), dim3(32,8), 0, stream>>>(L, rates, Aop2);
  k0c<<<dim3((496*512 + 255)/256), dim3(256), 0, stream>>>(rho0, Aop2, Bop2, dout, bar);

  const u16* WallC = Wall;
  void* args[] = { (void*)&WallC, (void*)&Aop2, (void*)&Bop2, (void*)&dout, (void*)&bar };
  hipError_t err = hipLaunchCooperativeKernel((const void*)evolve, dim3(256), dim3(256),
                                              args, 0, stream);
  if (err != hipSuccess){
    // fallback: R3 multi-launch path (identical math)
    gemm_nt_k<1><<<dim3(8,8), dim3(256), 0, stream>>>(Aop2, Aop2, 0, Aop2, Bop2);
    for (int s = 0; s < 32; ++s){
      int rhoKB  = 144 + 16*(s & 1);
      int rhoKBN = 144 + 16*((s+1) & 1);
      gemm_nt_k<0><<<dim3(62,8), dim3(256), 0, stream>>>(Wall, Bop2, rhoKB, Aop2, Bop2);
      phaseB_k<<<dim3(136), dim3(256), 0, stream>>>(Aop2, Bop2, dout, rhoKB, rhoKBN);
    }
  }
}

// Round 6
// 775.842 us; speedup vs baseline: 3.0576x; 3.0576x over previous
//
#include <hip/hip_runtime.h>

typedef unsigned short u16;
typedef __attribute__((ext_vector_type(8))) __bf16 bf16x8;
typedef __attribute__((ext_vector_type(4))) float f32x4;

#define DT_STEP 0.01f

// ---- workspace layout (bytes) ----
// All matrix operands live in "MFMA-staged layout": element (row, kk) of a
// [rows x K] K-major matrix is stored in 1KB blocks of 16 rows x 32 kk:
//   off_u16 = ((row>>4)*KB + (kk>>5))*512 + (((kk>>3)&3)*16 + (row&15))*8 + (kk&7)
// so a wave's MFMA fragment load is exactly 16B per lane at base + lane*16B.
//
// Wall : 3968 rows x 512 K (KB=16)  : row k*496+i = sqrt(r_k)*L_k[i,:]
// Aop2 : 496 rows x 5632 K (KB=176) : KB 0..127 = SwC (setup) then Tflat (steps)
//                                     KB 128..143 = -0.5*G
//                                     KB 144..159 = -0.5*rho slot0
//                                     KB 160..175 = -0.5*rho slot1
// Bop2 : 496 rows x 5632 K (KB=176) : KB 0..127 = SwT (sqrt(r_k)*L_k blocks)
//                                     KB 128..143 = G
//                                     KB 144..159 = rho slot0
//                                     KB 160..175 = rho slot1
// pad  : keeps benign OOB reads of row-block 31 (rows 496..511, results
//        discarded by row<496 guards) inside the mapped workspace.
static const size_t OFF_WALL = 0;
static const size_t OFF_AOP2 = 4063232;    // 248*16*512*2
static const size_t OFF_BOP2 = 9650176;    // + 31*176*512*2
static const size_t OFF_PAD  = 15237120;   // + 31*176*512*2
static const size_t WS_NEED  = 16221440;

static __device__ __forceinline__ u16 f2bf(float x){
  unsigned u = __float_as_uint(x);
  u = u + 0x7FFFu + ((u >> 16) & 1u);   // RNE
  return (u16)(u >> 16);
}

static __device__ __forceinline__ size_t stx(int row, int kk, int KB){
  return ((size_t)((row >> 4) * KB + (kk >> 5)) << 9)
       + (size_t)(((((kk >> 3) & 3) * 16) + (row & 15)) << 3) + (kk & 7);
}

// K0a: fill Wall (staged) and SwT region of Bop2 (staged). K-pads -> 0.
__global__ __launch_bounds__(256) void k0a(const float* __restrict__ L,
                                           const float* __restrict__ rates,
                                           u16* __restrict__ Wall,
                                           u16* __restrict__ Bop2){
  int id = blockIdx.x * 256 + threadIdx.x;
  if (id >= 8*496*512) return;
  int k   = id / (496*512);
  int rem = id - k*(496*512);
  int i   = rem >> 9;
  int j   = rem & 511;
  float rt = sqrtf(fabsf(rates[k]));
  float v = 0.0f;
  if (j < 496) v = rt * L[(size_t)k*246016 + i*496 + j];
  u16 h = f2bf(v);
  Wall[stx(k*496 + i, j, 16)] = h;
  Bop2[stx(i, (k << 9) + j, 176)] = h;
}

// K0b: SwC[i, k*512+j] = sqrt(r_k)*L_k[j,i] into Aop2 KB 0..127 (LDS transpose).
__global__ __launch_bounds__(256) void k0b(const float* __restrict__ L,
                                           const float* __restrict__ rates,
                                           u16* __restrict__ Aop2){
  __shared__ float tile[32][33];
  int k  = blockIdx.z;
  int i0 = blockIdx.x * 32;
  int j0 = blockIdx.y * 32;
  int tx = threadIdx.x, ty = threadIdx.y;  // 32 x 8
  float rt = sqrtf(fabsf(rates[k]));
  #pragma unroll
  for (int p = 0; p < 4; ++p){
    int j = j0 + ty + p*8;   // row of L_k
    int i = i0 + tx;         // col of L_k
    float v = 0.0f;
    if (j < 496 && i < 496) v = rt * L[(size_t)k*246016 + j*496 + i];
    tile[ty + p*8][tx] = v;
  }
  __syncthreads();
  #pragma unroll
  for (int p = 0; p < 4; ++p){
    int i = i0 + ty + p*8;   // SwC row
    int j = j0 + tx;         // col within k-block (pads get 0 via load guard)
    if (i < 496) Aop2[stx(i, (k << 9) + j, 176)] = f2bf(tile[tx][ty + p*8]);
  }
}

// K0c: rho into slot0 (staged), zero slot1 + G pads, d_out = rho0.
__global__ __launch_bounds__(256) void k0c(const float* __restrict__ rho0,
                                           u16* __restrict__ Aop2,
                                           u16* __restrict__ Bop2,
                                           float* __restrict__ dout){
  int id = blockIdx.x * 256 + threadIdx.x;
  if (id >= 496*512) return;
  int i = id >> 9, j = id & 511;
  float f = (j < 496) ? rho0[(size_t)i*496 + j] : 0.0f;
  Bop2[stx(i, 4608 + j, 176)] = f2bf(f);
  Aop2[stx(i, 4608 + j, 176)] = f2bf(-0.5f*f);
  Bop2[stx(i, 5120 + j, 176)] = 0;
  Aop2[stx(i, 5120 + j, 176)] = 0;
  if (j >= 496){ Bop2[stx(i, 4096 + j, 176)] = 0; Aop2[stx(i, 4096 + j, 176)] = 0; }
  if (j < 496) dout[(size_t)i*496 + j] = f;
}

// Direct-to-register NT GEMM tile job on staged operands, rotated register
// pipeline (DEPTH statically-indexed slots -> DEPTH*4 b128 loads in flight).
// MODE 0: phase A, T_k = L~_k * rho. NKT=16. Epilogue -> staged Tflat
//         (pad cols written as 0 -> no NaN hazard).
// MODE 1: G = SwC * SwC^T (once). NKT=128. Epilogue -> -0.5G / G staged.
template<int MODE>
static __device__ __forceinline__ void gemm_job(
    int tm, int tn, int rhoKB,
    const u16* __restrict__ Ast, const u16* __restrict__ Bst,
    u16* Aop2, u16* Bop2)
{
  const int t    = threadIdx.x;
  const int lane = t & 63;
  const int w    = t >> 6;
  const int wm   = w & 1, wn = w >> 1;

  constexpr int DEPTH = 4;
  constexpr int NKT   = (MODE == 0) ? 16 : 128;
  const int KBa = (MODE == 0) ? 16 : 176;
  const int RA0 = tm*4 + wm*2;
  const int RB0 = tn*4 + wn*2;
  const size_t laneu = (size_t)lane * 8;
  const size_t strA = (size_t)KBa << 9;
  const size_t strB = (size_t)176 << 9;
  const u16* baseA = Ast + (((size_t)RA0 * KBa) << 9) + laneu;
  const u16* baseB = Bst + (((size_t)RB0 * 176) << 9) + laneu
                   + ((MODE == 0) ? ((size_t)rhoKB << 9) : (size_t)0);

  bf16x8 Ar[DEPTH][2], Br[DEPTH][2];
  f32x4 acc[2][2];
  #pragma unroll
  for (int a = 0; a < 2; ++a)
    #pragma unroll
    for (int b = 0; b < 2; ++b)
      acc[a][b] = (f32x4){0.f, 0.f, 0.f, 0.f};

  #pragma unroll
  for (int p = 0; p < DEPTH; ++p){
    const u16* pa = baseA + ((size_t)p << 9);
    const u16* pb = baseB + ((size_t)p << 9);
    Ar[p][0] = *(const bf16x8*)(pa);
    Ar[p][1] = *(const bf16x8*)(pa + strA);
    Br[p][0] = *(const bf16x8*)(pb);
    Br[p][1] = *(const bf16x8*)(pb + strB);
  }
  for (int it = 0; it < NKT - DEPTH; it += DEPTH){
    #pragma unroll
    for (int p = 0; p < DEPTH; ++p){
      acc[0][0] = __builtin_amdgcn_mfma_f32_16x16x32_bf16(Ar[p][0], Br[p][0], acc[0][0], 0, 0, 0);
      acc[0][1] = __builtin_amdgcn_mfma_f32_16x16x32_bf16(Ar[p][0], Br[p][1], acc[0][1], 0, 0, 0);
      acc[1][0] = __builtin_amdgcn_mfma_f32_16x16x32_bf16(Ar[p][1], Br[p][0], acc[1][0], 0, 0, 0);
      acc[1][1] = __builtin_amdgcn_mfma_f32_16x16x32_bf16(Ar[p][1], Br[p][1], acc[1][1], 0, 0, 0);
      int kt = it + p + DEPTH;
      const u16* pa = baseA + ((size_t)kt << 9);
      const u16* pb = baseB + ((size_t)kt << 9);
      Ar[p][0] = *(const bf16x8*)(pa);
      Ar[p][1] = *(const bf16x8*)(pa + strA);
      Br[p][0] = *(const bf16x8*)(pb);
      Br[p][1] = *(const bf16x8*)(pb + strB);
    }
  }
  #pragma unroll
  for (int p = 0; p < DEPTH; ++p){
    acc[0][0] = __builtin_amdgcn_mfma_f32_16x16x32_bf16(Ar[p][0], Br[p][0], acc[0][0], 0, 0, 0);
    acc[0][1] = __builtin_amdgcn_mfma_f32_16x16x32_bf16(Ar[p][0], Br[p][1], acc[0][1], 0, 0, 0);
    acc[1][0] = __builtin_amdgcn_mfma_f32_16x16x32_bf16(Ar[p][1], Br[p][0], acc[1][0], 0, 0, 0);
    acc[1][1] = __builtin_amdgcn_mfma_f32_16x16x32_bf16(Ar[p][1], Br[p][1], acc[1][1], 0, 0, 0);
  }

  const int quad = lane >> 4, c16 = lane & 15;
  #pragma unroll
  for (int mi = 0; mi < 2; ++mi)
  #pragma unroll
  for (int ni = 0; ni < 2; ++ni)
  #pragma unroll
  for (int r = 0; r < 4; ++r){
    int row = tm*64 + wm*32 + mi*16 + quad*4 + r;
    int col = tn*64 + wn*32 + ni*16 + c16;
    float v = acc[mi][ni][r];
    if (MODE == 0){
      int k  = row / 496;
      int i2 = row - k*496;
      u16 hv = (col < 496) ? f2bf(v) : (u16)0;   // zero pads: no NaN into Tflat
      Aop2[stx(i2, (k << 9) + col, 176)] = hv;
    } else {
      if (row < 496 && col < 496){
        Bop2[stx(row, 4096 + col, 176)] = f2bf(v);
        Aop2[stx(row, 4096 + col, 176)] = f2bf(-0.5f*v);
      }
    }
  }
}

// Phase A kernel with XCD-aware job map: grid 512 1-D; x=b&7 is the XCD
// (dispatch round-robin heuristic), tm = x*8 + ((b>>3)&7) so XCD x streams
// only its 512 KB Wall slice; tn = (b>>3)>>3. tm>=62 -> idle (16 blocks).
__global__ __launch_bounds__(256, 2) void phaseA_k(
    const u16* __restrict__ Wall, const u16* __restrict__ Bop2src,
    int rhoKB, u16* Aop2, u16* Bop2){
  int b = blockIdx.x;
  int x = b & 7, i = b >> 3;
  int tm = x*8 + (i & 7);
  int tn = i >> 3;
  if (tm >= 62) return;
  gemm_job<0>(tm, tn, rhoKB, Wall, Bop2src, Aop2, Bop2);
}

__global__ __launch_bounds__(256, 2) void gemmG_k(
    const u16* __restrict__ Ast, u16* Aop2, u16* Bop2){
  gemm_job<1>(blockIdx.x, blockIdx.y, 0, Ast, Ast, Aop2, Bop2);
}

// Phase-B pair decode with XCD grouping: the 16 row-blocks (32 rows each)
// form 4 quadrants; 6 off-diagonal quadrant-pair groups (16 pairs each) pin
// to XCDs 0..5, the two diagonal groups (20 pairs) to XCDs 6/7 with 3 pairs
// each borrowed by XCDs 0..2 / 3..5. Each XCD touches ~8 row-blocks of each
// operand instead of all 16 -> ~2x less L2 refill traffic.
static __device__ __forceinline__ void pairDecode(int b, int& tm, int& tn){
  const int x = b & 7;      // intended XCD
  const int o = b >> 3;     // 0..16
  if (x < 6 && o < 16){
    const int qa[6] = {0,0,0,1,1,2};
    const int qb[6] = {1,2,3,2,3,3};
    tm = qa[x]*4 + (o >> 2);
    tn = qb[x]*4 + (o & 3);
  } else {
    int n, grp;             // grp 0 -> (Q0,Q0)+(Q1,Q1), grp 1 -> (Q2,Q2)+(Q3,Q3)
    if (x == 6){ grp = 0; n = o; }
    else if (x == 7){ grp = 1; n = o; }
    else if (x < 3){ grp = 0; n = 17 + x; }       // o==16, x in 0..2
    else { grp = 1; n = 17 + (x - 3); }           // o==16, x in 3..5
    int qbase = (grp == 0) ? ((n < 10) ? 0 : 1) : ((n < 10) ? 2 : 3);
    int m = (n < 10) ? n : n - 10;
    int ii = 0;
    while (m >= 4 - ii){ m -= 4 - ii; ++ii; }     // tri decode over 4 elems
    tm = qbase*4 + ii;
    tn = qbase*4 + ii + m;
  }
}

// Phase B: rho += DT*( sum_k T_k L~_k^T - 0.5(G rho + rho G) ), symmetric C.
// 136 blocks = lower-tri pairs of 32x32 C-tiles (XCD-grouped). Full K=5120
// split across the block's 4 waves (DEPTH=5 register pipeline), LDS reduce,
// inline finalize (fp32 rho in d_out + staged bf16 rho + mirror tile).
__global__ __launch_bounds__(256, 1) void phaseB_k(
    u16* Aop2, u16* Bop2, float* dout, int rhoKB, int rhoKBN)
{
  __shared__ float red[4][32][33];
  const int t = threadIdx.x, lane = t & 63, w = t >> 6;
  int tm, tn;
  pairDecode(blockIdx.x, tm, tn);            // tm <= tn

  const int kt0 = w * 40;                    // per-wave K slice (40 kt of 32)
  const size_t laneu = (size_t)lane * 8;
  const size_t str = (size_t)176 << 9;
  const u16* baseA = (const u16*)Aop2 + (((size_t)(tm*2) * 176) << 9) + laneu;
  const u16* baseB = (const u16*)Bop2 + (((size_t)(tn*2) * 176) << 9) + laneu;

  auto colmap = [&](int kt, int& ka, int& kb){
    if (kt < 128)      { ka = kt;               kb = kt; }             // T x SwT
    else if (kt < 144) { ka = kt;               kb = rhoKB + kt-128; } // -G/2 x rho
    else               { ka = rhoKB + kt - 144; kb = kt - 16; }        // -rho/2 x G
  };

  constexpr int DEPTH = 5;
  bf16x8 Ar[DEPTH][2], Br[DEPTH][2];
  f32x4 acc[2][2];
  #pragma unroll
  for (int a = 0; a < 2; ++a)
    #pragma unroll
    for (int c = 0; c < 2; ++c)
      acc[a][c] = (f32x4){0.f, 0.f, 0.f, 0.f};

  #pragma unroll
  for (int p = 0; p < DEPTH; ++p){
    int ka, kb; colmap(kt0 + p, ka, kb);
    const u16* pa = baseA + ((size_t)ka << 9);
    const u16* pb = baseB + ((size_t)kb << 9);
    Ar[p][0] = *(const bf16x8*)(pa);
    Ar[p][1] = *(const bf16x8*)(pa + str);
    Br[p][0] = *(const bf16x8*)(pb);
    Br[p][1] = *(const bf16x8*)(pb + str);
  }
  for (int it = 0; it < 40 - DEPTH; it += DEPTH){
    #pragma unroll
    for (int p = 0; p < DEPTH; ++p){
      acc[0][0] = __builtin_amdgcn_mfma_f32_16x16x32_bf16(Ar[p][0], Br[p][0], acc[0][0], 0, 0, 0);
      acc[0][1] = __builtin_amdgcn_mfma_f32_16x16x32_bf16(Ar[p][0], Br[p][1], acc[0][1], 0, 0, 0);
      acc[1][0] = __builtin_amdgcn_mfma_f32_16x16x32_bf16(Ar[p][1], Br[p][0], acc[1][0], 0, 0, 0);
      acc[1][1] = __builtin_amdgcn_mfma_f32_16x16x32_bf16(Ar[p][1], Br[p][1], acc[1][1], 0, 0, 0);
      int ka, kb; colmap(kt0 + it + p + DEPTH, ka, kb);
      const u16* pa = baseA + ((size_t)ka << 9);
      const u16* pb = baseB + ((size_t)kb << 9);
      Ar[p][0] = *(const bf16x8*)(pa);
      Ar[p][1] = *(const bf16x8*)(pa + str);
      Br[p][0] = *(const bf16x8*)(pb);
      Br[p][1] = *(const bf16x8*)(pb + str);
    }
  }
  #pragma unroll
  for (int p = 0; p < DEPTH; ++p){
    acc[0][0] = __builtin_amdgcn_mfma_f32_16x16x32_bf16(Ar[p][0], Br[p][0], acc[0][0], 0, 0, 0);
    acc[0][1] = __builtin_amdgcn_mfma_f32_16x16x32_bf16(Ar[p][0], Br[p][1], acc[0][1], 0, 0, 0);
    acc[1][0] = __builtin_amdgcn_mfma_f32_16x16x32_bf16(Ar[p][1], Br[p][0], acc[1][0], 0, 0, 0);
    acc[1][1] = __builtin_amdgcn_mfma_f32_16x16x32_bf16(Ar[p][1], Br[p][1], acc[1][1], 0, 0, 0);
  }

  const int quad = lane >> 4, c16 = lane & 15;
  #pragma unroll
  for (int mi = 0; mi < 2; ++mi)
  #pragma unroll
  for (int ni = 0; ni < 2; ++ni)
  #pragma unroll
  for (int r = 0; r < 4; ++r)
    red[w][mi*16 + quad*4 + r][ni*16 + c16] = acc[mi][ni][r];
  __syncthreads();

  #pragma unroll
  for (int c = t; c < 1024; c += 256){
    int lr = c >> 5, lc = c & 31;
    float sum = red[0][lr][lc] + red[1][lr][lc] + red[2][lr][lc] + red[3][lr][lc];
    int row = tm*32 + lr, col = tn*32 + lc;
    if (row < 496 && col < 496){
      int e = row*496 + col;
      float rnew = dout[e] + DT_STEP * sum;
      u16 hb = f2bf(rnew), ha = f2bf(-0.5f*rnew);
      dout[e] = rnew;
      Bop2[stx(row, (rhoKBN << 5) + col, 176)] = hb;
      Aop2[stx(row, (rhoKBN << 5) + col, 176)] = ha;
      if (tm != tn){
        dout[col*496 + row] = rnew;
        Bop2[stx(col, (rhoKBN << 5) + row, 176)] = hb;
        Aop2[stx(col, (rhoKBN << 5) + row, 176)] = ha;
      }
    }
  }
}

extern "C" void kernel_launch(void* const* d_in, const int* in_sizes, int n_in,
                              void* d_out, int out_size, void* d_ws, size_t ws_size,
                              hipStream_t stream)
{
  (void)in_sizes; (void)n_in; (void)out_size;
  if (ws_size < WS_NEED) return;
  const float* rho0  = (const float*)d_in[0];
  // d_in[1] (H_real) provably does not affect the real forward output.
  const float* L     = (const float*)d_in[2];
  const float* rates = (const float*)d_in[3];
  float* dout = (float*)d_out;
  char* ws = (char*)d_ws;
  u16* Wall = (u16*)(ws + OFF_WALL);
  u16* Aop2 = (u16*)(ws + OFF_AOP2);
  u16* Bop2 = (u16*)(ws + OFF_BOP2);

  k0a<<<dim3((8*496*512 + 255)/256), dim3(256), 0, stream>>>(L, rates, Wall, Bop2);
  k0b<<<dim3(16,16,8), dim3(32,8), 0, stream>>>(L, rates, Aop2);
  k0c<<<dim3((496*512 + 255)/256), dim3(256), 0, stream>>>(rho0, Aop2, Bop2, dout);
  // G = sum_k r_k L_k^T L_k  (once)
  gemmG_k<<<dim3(8,8), dim3(256), 0, stream>>>(Aop2, Aop2, Bop2);

  for (int s = 0; s < 32; ++s){
    int rhoKB  = 144 + 16*(s & 1);
    int rhoKBN = 144 + 16*((s+1) & 1);
    // phase A: T_k = sqrt(r_k) L_k * rho  (XCD-sliced Wall reads)
    phaseA_k<<<dim3(512), dim3(256), 0, stream>>>(Wall, Bop2, rhoKB, Aop2, Bop2);
    // phase B: symmetric update, XCD-grouped pairs, no cross-block comm
    phaseB_k<<<dim3(136), dim3(256), 0, stream>>>(Aop2, Bop2, dout, rhoKB, rhoKBN);
  }
}